// Round 13
// baseline (92.122 us; speedup 1.0000x reference)
//
#include <hip/hip_runtime.h>
#include <cstdint>
#include <cstddef>

#define BN 4
#define CN 64
#define NN 4096
#define GN 32
#define TN 77
#define DN 768
#define EPSV 1e-5f
#define SCALEV 0.125f
#define LOG2E 1.4426950408889634f
#define NSPLIT 8

typedef __bf16 bf16_t;
typedef __attribute__((ext_vector_type(8))) __bf16 bf16x8;
typedef __attribute__((ext_vector_type(4))) __bf16 bf16x4;
typedef __attribute__((ext_vector_type(4))) float f32x4;

#define EXP2(x) __builtin_amdgcn_exp2f(x)

__device__ __forceinline__ f32x4 mfma16(bf16x8 a, bf16x8 b, f32x4 c) {
  return __builtin_amdgcn_mfma_f32_16x16x32_bf16(a, b, c, 0, 0, 0);
}
__device__ __forceinline__ f32x4 zero4() { return (f32x4){0.f, 0.f, 0.f, 0.f}; }

// async global->LDS, 16B per lane; LDS dest is wave-uniform base + lane*16
__device__ __forceinline__ void gload16(const void* g, void* l) {
  __builtin_amdgcn_global_load_lds(
      (const __attribute__((address_space(1))) void*)g,
      (__attribute__((address_space(3))) void*)l, 16, 0, 0);
}

// fragment-order channel permutation for 64-ch rows (two K=32 frags)
__device__ __forceinline__ int fragpos(int o) {
  return ((o >> 2) & 3) * 16 + ((o >> 4) & 1) * 4 + ((o >> 5) & 1) * 8 + (o & 3);
}
// within-64 K-slot permutation (two K=32 chunks)
__device__ __forceinline__ int vperm(int p) {
  return (p & 32) + ((p >> 2) & 3) * 8 + ((p >> 4) & 1) * 4 + (p & 3);
}
// within-96 K-slot permutation (three K=32 chunks)
__device__ __forceinline__ int perm96(int t) {
  int u = t & 31;
  return (t & ~31) + (((u & 15) >> 2) << 3) + ((u >> 4) << 2) + (u & 3);
}

// ---------------- K1: GN partial stats (blocks 0-255) + tk/tv (blocks 256-639) ---------
__global__ __launch_bounds__(256) void k_pre(const float* __restrict__ x,
    float* __restrict__ gpart,
    const float* __restrict__ ctx,
    const float* __restrict__ wk, const float* __restrict__ bk,
    const float* __restrict__ wv, const float* __restrict__ bv,
    bf16_t* __restrict__ tko, bf16_t* __restrict__ tvo) {
  __shared__ float ss[4], ssq[4];
  __shared__ float cr[768];
  __shared__ float red[4][64];
  int bx = blockIdx.x;
  int tid = threadIdx.x;
  if (bx < 256) {
    const float4* base = reinterpret_cast<const float4*>(x + (size_t)bx * 4096);
    float s = 0.f, sq = 0.f;
    for (int i = tid; i < 1024; i += 256) {
      float4 v = base[i];
      s  += v.x + v.y + v.z + v.w;
      sq += v.x*v.x + v.y*v.y + v.z*v.z + v.w*v.w;
    }
    for (int off = 32; off; off >>= 1) { s += __shfl_down(s, off); sq += __shfl_down(sq, off); }
    int w = tid >> 6, l = tid & 63;
    if (l == 0) { ss[w] = s; ssq[w] = sq; }
    __syncthreads();
    if (tid == 0) {
      gpart[bx * 2]     = ss[0] + ss[1] + ss[2] + ss[3];
      gpart[bx * 2 + 1] = ssq[0] + ssq[1] + ssq[2] + ssq[3];
    }
    return;
  }
  int bt = bx - 256;
  int b = bt / 96, t = bt % 96;
  if (t >= 77) {
    if (tid < 64) {
      if (t < 80) tko[((size_t)(b * 80) + t) * 64 + tid] = (bf16_t)0.f;
      tvo[((size_t)(b * 64) + tid) * 96 + perm96(t)] = (bf16_t)0.f;
    }
    return;
  }
  const float* src = ctx + ((size_t)(b * TN) + t) * 768;
  for (int i = tid; i < 768; i += 256) cr[i] = src[i];
  __syncthreads();
  int o = tid & 63, sec = tid >> 6;
  int sel = sec & 1, dh = sec >> 1;
  const float* w = (sel ? wv : wk) + dh * 384 * 64;
  const float* c0 = cr + dh * 384;
  float acc = 0.f;
  for (int d = 0; d < 384; d++) acc += c0[d] * w[d * 64 + o];
  red[sec][o] = acc;
  __syncthreads();
  if (tid < 128) {
    int s2 = tid >> 6; int oo = tid & 63;
    float r = red[s2][oo] + red[s2 + 2][oo] + (s2 ? bv[oo] : bk[oo]);
    if (s2 == 0)
      tko[((size_t)(b * 80) + t) * 64 + (fragpos(oo) ^ ((t & 7) << 3))] = (bf16_t)r;
    else
      tvo[((size_t)(b * 64) + oo) * 96 + perm96(t)] = (bf16_t)r;
  }
}

// ---------------- K2: GN apply + QKV 1x1; 32-position tiles (512 blocks) ----------------
__global__ __launch_bounds__(256) void k_gn_qkv(const float* __restrict__ x,
    const float* __restrict__ gpart,
    const float* __restrict__ gns, const float* __restrict__ gnb,
    const float* __restrict__ qkvw, const float* __restrict__ qkvb,
    bf16_t* __restrict__ qb, bf16_t* __restrict__ kb, bf16_t* __restrict__ vT) {
  __shared__ float hn[64][36];
  __shared__ float wqkT[64][129];
  __shared__ float wv2[64][64];
  int bx = blockIdx.x; int b = bx >> 7; int t0 = (bx & 127) << 5;
  int tid = threadIdx.x;
  for (int i = tid; i < 2048; i += 256) {
    float4 v = reinterpret_cast<const float4*>(qkvw)[i];
    int base = i << 2; int o = base >> 6, cc = base & 63;
    wqkT[cc][o] = v.x; wqkT[cc + 1][o] = v.y; wqkT[cc + 2][o] = v.z; wqkT[cc + 3][o] = v.w;
  }
  for (int i = tid; i < 1024; i += 256) {
    float4 v = reinterpret_cast<const float4*>(qkvw + 8192)[i];
    int base = i << 2; int ch = base >> 6, cc = base & 63;
    *reinterpret_cast<float4*>(&wv2[ch][cc]) = v;
  }
  {
    int c = tid >> 2, p0 = (tid & 3) << 3;
    float4 gp = *reinterpret_cast<const float4*>(gpart + (((b << 5) + (c >> 1)) << 2));
    float mu = (gp.x + gp.z) * (1.f / 8192.f);
    float e2 = (gp.y + gp.w) * (1.f / 8192.f);
    float rs = rsqrtf(e2 - mu * mu + EPSV);
    float sc = gns[c] * rs, bi = gnb[c] - mu * sc;
    const float* xp = x + ((size_t)(b * 64 + c)) * NN + t0 + p0;
    float4 v1 = *reinterpret_cast<const float4*>(xp);
    float4 v2 = *reinterpret_cast<const float4*>(xp + 4);
    hn[c][p0+0] = v1.x*sc+bi; hn[c][p0+1] = v1.y*sc+bi;
    hn[c][p0+2] = v1.z*sc+bi; hn[c][p0+3] = v1.w*sc+bi;
    hn[c][p0+4] = v2.x*sc+bi; hn[c][p0+5] = v2.y*sc+bi;
    hn[c][p0+6] = v2.z*sc+bi; hn[c][p0+7] = v2.w*sc+bi;
  }
  __syncthreads();
  {
    int o0 = tid & 63, p0 = (tid >> 6) << 3;
    int pq = fragpos(o0);
    float acc0[8], acc1[8];
    float b0 = qkvb[o0], b1 = qkvb[64 + o0];
    #pragma unroll
    for (int m = 0; m < 8; m++) { acc0[m] = b0; acc1[m] = b1; }
    for (int cc = 0; cc < 64; ++cc) {
      float4 h0 = *reinterpret_cast<const float4*>(&hn[cc][p0]);
      float4 h1 = *reinterpret_cast<const float4*>(&hn[cc][p0 + 4]);
      float w0 = wqkT[cc][o0];
      float w1 = wqkT[cc][64 + o0];
      acc0[0] += h0.x*w0; acc0[1] += h0.y*w0; acc0[2] += h0.z*w0; acc0[3] += h0.w*w0;
      acc0[4] += h1.x*w0; acc0[5] += h1.y*w0; acc0[6] += h1.z*w0; acc0[7] += h1.w*w0;
      acc1[0] += h0.x*w1; acc1[1] += h0.y*w1; acc1[2] += h0.z*w1; acc1[3] += h0.w*w1;
      acc1[4] += h1.x*w1; acc1[5] += h1.y*w1; acc1[6] += h1.z*w1; acc1[7] += h1.w*w1;
    }
    size_t rowbase = ((size_t)(b * NN) + t0 + p0) << 6;
    #pragma unroll
    for (int j = 0; j < 8; j++) {
      qb[rowbase + ((size_t)j << 6) + pq] = (bf16_t)(acc0[j] * (SCALEV * LOG2E));
      kb[rowbase + ((size_t)j << 6) + (pq ^ (j << 3))] = (bf16_t)acc1[j];
    }
  }
  {
    int p2 = tid & 31, ob = tid >> 5;
    int kk = t0 + p2;
    int colsw = vperm(kk & 63) ^ (ob << 3);
    float acc[8];
    #pragma unroll
    for (int m = 0; m < 8; m++) acc[m] = qkvb[128 + ob + 8*m];
    for (int c0 = 0; c0 < 64; c0 += 4) {
      float h0 = hn[c0][p2], h1 = hn[c0+1][p2], h2 = hn[c0+2][p2], h3 = hn[c0+3][p2];
      #pragma unroll
      for (int m = 0; m < 8; m++) {
        float4 w4 = *reinterpret_cast<const float4*>(&wv2[ob + 8*m][c0]);
        acc[m] += h0*w4.x + h1*w4.y + h2*w4.z + h3*w4.w;
      }
    }
    size_t vbase = ((size_t)(b * 64)) * NN + (size_t)(kk & ~63) + colsw;
    #pragma unroll
    for (int m = 0; m < 8; m++)
      vT[vbase + (size_t)(ob + 8*m) * NN] = (bf16_t)acc[m];
  }
}

// ---------------- K3: flash self-attn, 64 q-rows/wave, LDS dbuf, KV-split x8 -----------
// grid 512 (2 blocks/CU). Straight-line online softmax (always rescale; no branches).
__global__ __launch_bounds__(256) void k_attn(const bf16_t* __restrict__ qb,
    const bf16_t* __restrict__ kb, const bf16_t* __restrict__ vT,
    bf16_t* __restrict__ opart, float* __restrict__ mpart, float* __restrict__ lpart) {
  __shared__ __align__(16) bf16_t smem[2][8192];
  int bx = blockIdx.x;
  int xcd = bx & 7;
  int b = xcd >> 1;
  int inner = ((bx >> 3) << 1) | (xcd & 1);    // 0..127
  int split = inner >> 4;                      // 0..7
  int qblk = inner & 15;                       // 0..15
  int tid = threadIdx.x; int w = tid >> 6, l = tid & 63;
  int lo = l & 15, g = l >> 4;
  int qbase = (qblk << 8) + (w << 6);          // 64 rows per wave
  bf16x8 qf[4][2];
  #pragma unroll
  for (int F = 0; F < 4; F++) {
    const bf16_t* qrow = qb + (((size_t)(b * NN) + qbase + F * 16 + lo) << 6) + g * 16;
    qf[F][0] = *reinterpret_cast<const bf16x8*>(qrow);
    qf[F][1] = *reinterpret_cast<const bf16x8*>(qrow + 8);
  }
  f32x4 oacc[4][4];
  #pragma unroll
  for (int F = 0; F < 4; F++)
    #pragma unroll
    for (int nt = 0; nt < 4; nt++) oacc[F][nt] = zero4();
  float m_[4] = {-8.f, -8.f, -8.f, -8.f};
  float l_[4] = {0.f, 0.f, 0.f, 0.f};
  const bf16_t* kbB = kb + ((size_t)b * NN << 6);
  const bf16_t* vB  = vT + ((size_t)b * 64) * NN;
  int kt0 = split << 9;                        // 512 keys per split

  int off0 = tid * 8;
  int off1 = 2048 + tid * 8;
  int ch0 = off0 >> 6, sl0 = off0 & 63;
  int ch1 = off1 >> 6, sl1 = off1 & 63;

  {
    const bf16_t* kT = kbB + ((size_t)kt0 << 6);
    gload16(kT + off0, &smem[0][off0]);
    gload16(kT + off1, &smem[0][off1]);
    gload16(vB + (size_t)ch0 * NN + kt0 + sl0, &smem[0][4096 + off0]);
    gload16(vB + (size_t)ch1 * NN + kt0 + sl1, &smem[0][4096 + off1]);
  }
  __syncthreads();

  #pragma unroll 1
  for (int t = 0; t < 8; ++t) {
    int cur = t & 1;
    if (t < 7) {
      int kn = kt0 + ((t + 1) << 6);
      const bf16_t* kT = kbB + ((size_t)kn << 6);
      gload16(kT + off0, &smem[cur ^ 1][off0]);
      gload16(kT + off1, &smem[cur ^ 1][off1]);
      gload16(vB + (size_t)ch0 * NN + kn + sl0, &smem[cur ^ 1][4096 + off0]);
      gload16(vB + (size_t)ch1 * NN + kn + sl1, &smem[cur ^ 1][4096 + off1]);
    }
    const bf16_t* sK = smem[cur];
    const bf16_t* sV = smem[cur] + 4096;
    // QK^T for 4 q-fragments; K loads shared
    f32x4 s[4][4];   // [F][c]
    #pragma unroll
    for (int c = 0; c < 4; c++) {
      int kk = (c << 4) + lo;
      int o1 = (g << 4) ^ ((kk & 7) << 3);
      bf16x8 kf0 = *reinterpret_cast<const bf16x8*>(sK + (kk << 6) + o1);
      bf16x8 kf1 = *reinterpret_cast<const bf16x8*>(sK + (kk << 6) + (o1 ^ 8));
      #pragma unroll
      for (int F = 0; F < 4; F++) {
        s[F][c] = mfma16(kf0, qf[F][0], zero4());
        s[F][c] = mfma16(kf1, qf[F][1], s[F][c]);
      }
    }
    // always-rescale online softmax, straight-line (no branches)
    #pragma unroll
    for (int F = 0; F < 4; F++) {
      float pmax = -1e30f;
      #pragma unroll
      for (int c = 0; c < 4; c++)
        #pragma unroll
        for (int r = 0; r < 4; r++) pmax = fmaxf(pmax, s[F][c][r]);
      pmax = fmaxf(pmax, __shfl_xor(pmax, 16));
      pmax = fmaxf(pmax, __shfl_xor(pmax, 32));
      float mn = fmaxf(m_[F], pmax);
      float corr = EXP2(m_[F] - mn);
      l_[F] *= corr; m_[F] = mn;
      float fr[4];
      #pragma unroll
      for (int r = 0; r < 4; r++) fr[r] = __shfl(corr, (g << 2) + r);
      #pragma unroll
      for (int nt = 0; nt < 4; nt++)
        #pragma unroll
        for (int r = 0; r < 4; r++) oacc[F][nt][r] *= fr[r];
    }
    // V f=0 loads early; exp VALU hides latency
    bf16x8 vf[4];
    #pragma unroll
    for (int nt = 0; nt < 4; nt++) {
      int ch = lo + (nt << 4);
      vf[nt] = *reinterpret_cast<const bf16x8*>(sV + (ch << 6) + ((g ^ (ch & 7)) << 3));
    }
    // exp + lane-local l accumulation
    #pragma unroll
    for (int F = 0; F < 4; F++) {
      float ls0 = 0.f, ls1 = 0.f;
      #pragma unroll
      for (int c = 0; c < 4; c++)
        #pragma unroll
        for (int r = 0; r < 4; r++) {
          float pv = EXP2(s[F][c][r] - m_[F]);
          s[F][c][r] = pv;
          if (c & 1) ls1 += pv; else ls0 += pv;
        }
      l_[F] += ls0 + ls1;
    }
    // P -> bf16 A fragments
    bf16x8 pa[4][2];
    #pragma unroll
    for (int F = 0; F < 4; F++)
      #pragma unroll
      for (int i = 0; i < 8; i++) {
        pa[F][0][i] = (bf16_t)s[F][i >> 2][i & 3];
        pa[F][1][i] = (bf16_t)s[F][2 + (i >> 2)][i & 3];
      }
    // PV f=0
    #pragma unroll
    for (int nt = 0; nt < 4; ++nt)
      #pragma unroll
      for (int F = 0; F < 4; F++)
        oacc[F][nt] = mfma16(pa[F][0], vf[nt], oacc[F][nt]);
    // V f=1 + PV f=1
    #pragma unroll
    for (int nt = 0; nt < 4; nt++) {
      int ch = lo + (nt << 4);
      vf[nt] = *reinterpret_cast<const bf16x8*>(sV + (ch << 6) + (((4 + g) ^ (ch & 7)) << 3));
    }
    #pragma unroll
    for (int nt = 0; nt < 4; ++nt)
      #pragma unroll
      for (int F = 0; F < 4; F++)
        oacc[F][nt] = mfma16(pa[F][1], vf[nt], oacc[F][nt]);
    __syncthreads();
  }

  #pragma unroll
  for (int F = 0; F < 4; F++) {
    l_[F] += __shfl_xor(l_[F], 16);
    l_[F] += __shfl_xor(l_[F], 32);
  }

  size_t ob = ((size_t)(split * BN + b)) * NN + qbase;
  #pragma unroll
  for (int F = 0; F < 4; F++) {
    float li[4];
    #pragma unroll
    for (int r = 0; r < 4; r++) li[r] = 1.0f / __shfl(l_[F], (g << 2) + r);
    #pragma unroll
    for (int nt = 0; nt < 4; nt++)
      #pragma unroll
      for (int r = 0; r < 4; r++)
        opart[((ob + F * 16 + (g << 2) + r) << 6) + lo + (nt << 4)] =
            (bf16_t)(oacc[F][nt][r] * li[r]);
  }
  if (l < 16)      { mpart[ob + lo] = m_[0];      lpart[ob + lo] = l_[0]; }
  else if (l < 32) { mpart[ob + 16 + lo] = m_[1]; lpart[ob + 16 + lo] = l_[1]; }
  else if (l < 48) { mpart[ob + 32 + lo] = m_[2]; lpart[ob + 32 + lo] = l_[2]; }
  else             { mpart[ob + 48 + lo] = m_[3]; lpart[ob + 48 + lo] = l_[3]; }
}

// ---------------- K4: combine 8 splits + proj + residual ; LayerNorm ; tq(bf16) --------
__global__ __launch_bounds__(256) void k_proj_ln_tq(const float* __restrict__ x,
    const bf16_t* __restrict__ opart, const float* __restrict__ mpart, const float* __restrict__ lpart,
    const float* __restrict__ projw, const float* __restrict__ projb,
    const float* __restrict__ lns, const float* __restrict__ lnb,
    const float* __restrict__ wq, const float* __restrict__ bq,
    float* __restrict__ h2, bf16_t* __restrict__ tq) {
  __shared__ float wcomb[16][NSPLIT];
  __shared__ float sob[16][65];
  __shared__ float h2l[64][17];
  __shared__ float r1[16][16], r2[16][16];
  __shared__ float mu_s[16], rs_s[16];
  int bx = blockIdx.x; int b = bx >> 8; int t0 = (bx & 255) << 4;
  int tid = threadIdx.x;
  if (tid < 16) {
    int p = tid, q = t0 + p;
    float ms[NSPLIT];
    float mstar = -1e30f;
    #pragma unroll
    for (int s = 0; s < NSPLIT; s++) {
      ms[s] = mpart[((size_t)(s * BN + b)) * NN + q];
      mstar = fmaxf(mstar, ms[s]);
    }
    float co[NSPLIT]; float denom = 0.f;
    #pragma unroll
    for (int s = 0; s < NSPLIT; s++) {
      co[s] = EXP2(ms[s] - mstar) * lpart[((size_t)(s * BN + b)) * NN + q];
      denom += co[s];
    }
    float inv = 1.0f / denom;
    #pragma unroll
    for (int s = 0; s < NSPLIT; s++) wcomb[p][s] = co[s] * inv;
  }
  __syncthreads();
  {
    int p = tid >> 4, c0 = (tid & 15) << 2;
    int q = t0 + p;
    float acc[4] = {0.f, 0.f, 0.f, 0.f};
    #pragma unroll
    for (int s = 0; s < NSPLIT; s++) {
      bf16x4 v = *reinterpret_cast<const bf16x4*>(
          opart + ((((size_t)(s * BN + b)) * NN + q) << 6) + c0);
      float wv = wcomb[p][s];
      #pragma unroll
      for (int j = 0; j < 4; j++) acc[j] += wv * (float)v[j];
    }
    #pragma unroll
    for (int j = 0; j < 4; j++) sob[p][c0 + j] = acc[j];
  }
  __syncthreads();
  {
    int p = tid & 15, ob = tid >> 4;
    float acc[4];
    #pragma unroll
    for (int m = 0; m < 4; m++) {
      int o = ob + 16*m;
      acc[m] = projb[o] + x[((size_t)(b * 64) + o) * NN + t0 + p];
    }
    for (int cc = 0; cc < 64; ++cc) {
      float sv = sob[p][cc];
      #pragma unroll
      for (int m = 0; m < 4; m++) acc[m] += sv * projw[(ob + 16*m) * 64 + cc];
    }
    #pragma unroll
    for (int m = 0; m < 4; m++) {
      int o = ob + 16*m;
      h2[((size_t)(b * 64) + o) * NN + t0 + p] = acc[m];
      h2l[o][p] = acc[m];
    }
  }
  __syncthreads();
  {
    int p = tid & 15, og = tid >> 4;
    float s = 0.f, sq = 0.f;
    #pragma unroll
    for (int j = 0; j < 4; j++) { float v = h2l[og * 4 + j][p]; s += v; sq += v*v; }
    r1[og][p] = s; r2[og][p] = sq;
  }
  __syncthreads();
  if (tid < 16) {
    float s = 0.f, sq = 0.f;
    #pragma unroll
    for (int j = 0; j < 16; j++) { s += r1[j][tid]; sq += r2[j][tid]; }
    float mu = s * (1.f/64.f);
    float var = sq * (1.f/64.f) - mu*mu;
    mu_s[tid] = mu; rs_s[tid] = rsqrtf(var + EPSV);
  }
  __syncthreads();
  {
    int p = tid & 15, cb = tid >> 4;
    float mu = mu_s[p], rs = rs_s[p];
    #pragma unroll
    for (int m = 0; m < 4; m++) {
      int c = cb + 16*m;
      sob[p][c] = (h2l[c][p] - mu) * rs * lns[c] + lnb[c];
    }
  }
  __syncthreads();
  {
    int o = tid & 63, pb = tid >> 6;
    int pq = fragpos(o);
    float acc[4];
    #pragma unroll
    for (int m = 0; m < 4; m++) acc[m] = bq[o];
    for (int cc = 0; cc < 64; ++cc) {
      float wv = wq[cc * 64 + o];
      #pragma unroll
      for (int m = 0; m < 4; m++) acc[m] += sob[pb + 4*m][cc] * wv;
    }
    #pragma unroll
    for (int m = 0; m < 4; m++) {
      int p = pb + 4*m;
      tq[(((size_t)(b * NN) + t0 + p) << 6) + pq] = (bf16_t)(acc[m] * (SCALEV * LOG2E));
    }
  }
}

// ---------------- K6: fused cross-attn (MFMA) + scramble GEMM + residual ----------------
// 256 blocks = (b, c1). 4 waves x 16 q-rows.
__global__ __launch_bounds__(256) void k_crossf(const bf16_t* __restrict__ tq,
    const bf16_t* __restrict__ tk, const bf16_t* __restrict__ tv,
    const float* __restrict__ wo, const float* __restrict__ bo,
    const float* __restrict__ h2, float* __restrict__ out) {
  __shared__ __align__(16) bf16_t tkl[80][64];    // swizzled rows (pre-swizzled source)
  __shared__ __align__(16) bf16_t tvl[64][104];   // [ch][tok96] padded pitch
  __shared__ __align__(16) bf16_t woT[64][64];    // [w][kperm] swizzled
  __shared__ __align__(16) bf16_t toutT[64][64];  // [c2][kperm] swizzled
  int bx = blockIdx.x; int b = bx >> 6; int c1 = bx & 63;
  int tid = threadIdx.x; int wv_ = tid >> 6; int l = tid & 63;
  int lo = l & 15, g = l >> 4;
  {
    const uint4* src = reinterpret_cast<const uint4*>(tk + (size_t)b * 80 * 64);
    uint4* dst = reinterpret_cast<uint4*>(&tkl[0][0]);
    for (int i = tid; i < 640; i += 256) dst[i] = src[i];
  }
  {
    const uint4* src = reinterpret_cast<const uint4*>(tv + (size_t)b * 64 * 96);
    uint4* dst = reinterpret_cast<uint4*>(&tvl[0][0]);
    for (int i = tid; i < 768; i += 256) {
      int row = i / 12, j = i % 12;
      dst[row * 13 + j] = src[i];
    }
  }
  for (int i = tid; i < 4096; i += 256) {
    int k = i >> 6, w = i & 63;
    int vp = vperm(k);
    woT[w][(((vp >> 3) ^ (w & 7)) << 3) + (vp & 7)] = (bf16_t)wo[i];
  }
  __syncthreads();
  // Q fragments (global, fragpos rows)
  int n0 = (c1 << 6) + (wv_ << 4);
  const bf16_t* qrow = tq + (((size_t)(b * NN) + n0 + lo) << 6) + g * 16;
  bf16x8 qf0 = *reinterpret_cast<const bf16x8*>(qrow);
  bf16x8 qf1 = *reinterpret_cast<const bf16x8*>(qrow + 8);
  // QK^T: 5 token-tiles
  f32x4 sa[5];
  #pragma unroll
  for (int ti = 0; ti < 5; ti++) {
    int tok = ti * 16 + lo;
    int o1 = (g << 4) ^ ((tok & 7) << 3);
    bf16x8 kf0 = *reinterpret_cast<const bf16x8*>(&tkl[tok][0] + o1);
    bf16x8 kf1 = *reinterpret_cast<const bf16x8*>(&tkl[tok][0] + (o1 ^ 8));
    f32x4 z = mfma16(kf0, qf0, zero4());
    sa[ti] = mfma16(kf1, qf1, z);
  }
  // one-shot masked softmax (lane lo = q; tokens at ti*16 + g*4 + r)
  float p[5][4];
  float mx = -1e30f;
  #pragma unroll
  for (int ti = 0; ti < 5; ti++)
    #pragma unroll
    for (int r = 0; r < 4; r++)
      if (ti * 16 + (g << 2) + r < TN) mx = fmaxf(mx, sa[ti][r]);
  mx = fmaxf(mx, __shfl_xor(mx, 16));
  mx = fmaxf(mx, __shfl_xor(mx, 32));
  float ls = 0.f;
  #pragma unroll
  for (int ti = 0; ti < 5; ti++)
    #pragma unroll
    for (int r = 0; r < 4; r++) {
      float pv = (ti * 16 + (g << 2) + r < TN) ? EXP2(sa[ti][r] - mx) : 0.f;
      p[ti][r] = pv; ls += pv;
    }
  ls += __shfl_xor(ls, 16); ls += __shfl_xor(ls, 32);
  float linv = 1.0f / ls;
  // P -> A fragments (3 chunks of K=32), zero-shuffle
  bf16x8 pa[3];
  #pragma unroll
  for (int c = 0; c < 3; c++)
    #pragma unroll
    for (int i = 0; i < 8; i++)
      pa[c][i] = (bf16_t)p[2 * c + (i >> 2)][i & 3];
  // PV: 3 chunks x 4 ch-tiles
  f32x4 oacc[4];
  #pragma unroll
  for (int nt = 0; nt < 4; nt++) oacc[nt] = zero4();
  #pragma unroll
  for (int c = 0; c < 3; c++)
    #pragma unroll
    for (int nt = 0; nt < 4; nt++) {
      bf16x8 vf = *reinterpret_cast<const bf16x8*>(&tvl[nt * 16 + lo][0] + c * 32 + g * 8);
      oacc[nt] = mfma16(pa[c], vf, oacc[nt]);
    }
  // normalize + write O^T to LDS (toutT[ch][vperm(qlocal)] with group swizzle)
  float li[4];
  #pragma unroll
  for (int r = 0; r < 4; r++) li[r] = __shfl(linv, (g << 2) + r);
  int hh = wv_ & 1, cp = wv_ >> 1;
  #pragma unroll
  for (int nt = 0; nt < 4; nt++) {
    int ch = nt * 16 + lo;
    int basegroup = cp * 4 + g;
    int col = ((basegroup ^ (ch & 7)) << 3) + hh * 4;
    bf16_t tmp[4];
    #pragma unroll
    for (int r = 0; r < 4; r++) tmp[r] = (bf16_t)(oacc[nt][r] * li[r]);
    *reinterpret_cast<uint2*>(&toutT[ch][col]) = *reinterpret_cast<const uint2*>(tmp);
  }
  __syncthreads();
  // final GEMM: D[c2 = wv*16 + ..., w] = toutT x woT ; wave owns 16 c2-rows
  f32x4 o2[4];
  #pragma unroll
  for (int wt = 0; wt < 4; wt++) o2[wt] = zero4();
  #pragma unroll
  for (int f = 0; f < 2; f++) {
    int c2r = wv_ * 16 + lo;
    int agrp = ((f * 4 + g) ^ (c2r & 7)) << 3;
    bf16x8 af = *reinterpret_cast<const bf16x8*>(&toutT[c2r][agrp]);
    #pragma unroll
    for (int wt = 0; wt < 4; wt++) {
      int wrow = wt * 16 + lo;
      int bgrp = ((f * 4 + g) ^ (wrow & 7)) << 3;
      bf16x8 bf_ = *reinterpret_cast<const bf16x8*>(&woT[wrow][bgrp]);
      o2[wt] = mfma16(af, bf_, o2[wt]);
    }
  }
  // epilogue: out = GEMM + h2 + bo
  const float* h2r = h2 + ((size_t)(b * 64) + c1) * NN;
  float* outr = out + ((size_t)(b * 64) + c1) * NN;
  float bov[4];
  #pragma unroll
  for (int wt = 0; wt < 4; wt++) bov[wt] = bo[wt * 16 + lo];
  #pragma unroll
  for (int wt = 0; wt < 4; wt++)
    #pragma unroll
    for (int r = 0; r < 4; r++) {
      int c2 = wv_ * 16 + (g << 2) + r;
      int pos = (c2 << 6) + wt * 16 + lo;
      outr[pos] = o2[wt][r] + h2r[pos] + bov[wt];
    }
}

extern "C" void kernel_launch(void* const* d_in, const int* in_sizes, int n_in,
                              void* d_out, int out_size, void* d_ws, size_t ws_size,
                              hipStream_t stream) {
  const float* x     = (const float*)d_in[0];
  const float* ctx   = (const float*)d_in[1];
  const float* gns   = (const float*)d_in[2];
  const float* gnb   = (const float*)d_in[3];
  const float* qkvw  = (const float*)d_in[4];
  const float* qkvb  = (const float*)d_in[5];
  const float* projw = (const float*)d_in[6];
  const float* projb = (const float*)d_in[7];
  const float* lns   = (const float*)d_in[8];
  const float* lnb   = (const float*)d_in[9];
  const float* wq    = (const float*)d_in[10];
  const float* bq    = (const float*)d_in[11];
  const float* wk    = (const float*)d_in[12];
  const float* bk    = (const float*)d_in[13];
  const float* wv    = (const float*)d_in[14];
  const float* bv    = (const float*)d_in[15];
  const float* wo    = (const float*)d_in[16];
  const float* bo    = (const float*)d_in[17];
  float* out = (float*)d_out;

  char* ws = (char*)d_ws;
  float* gpart = (float*)ws;                       // 2 KB
  bf16_t* qb   = (bf16_t*)(ws + 4096);             // 2 MB
  bf16_t* kbuf = qb + (size_t)BN * NN * 64;        // 2 MB (swizzled)
  bf16_t* vT   = kbuf + (size_t)BN * NN * 64;      // 2 MB (swizzled)
  bf16_t* opart = vT + (size_t)BN * NN * 64;       // 16 MB bf16 (8 splits)
  float* mpart = (float*)(opart + (size_t)NSPLIT * BN * NN * 64);   // 512 KB
  float* lpart = mpart + (size_t)NSPLIT * BN * NN;                  // 512 KB
  float* h2    = lpart + (size_t)NSPLIT * BN * NN;                  // 4 MB
  bf16_t* tkb16 = (bf16_t*)(h2 + (size_t)BN * NN * 64);             // 40 KB
  bf16_t* tvb16 = tkb16 + (size_t)BN * 80 * 64;                     // 48 KB
  // aliased: tq (bf16, 2 MB) over dead qb after k_attn
  bf16_t* tqb16 = qb;

  k_pre<<<dim3(256 + BN * 96), dim3(256), 0, stream>>>(x, gpart, ctx, wk, bk, wv, bv,
                                                       tkb16, tvb16);
  k_gn_qkv<<<dim3(512), dim3(256), 0, stream>>>(x, gpart, gns, gnb, qkvw, qkvb,
                                                qb, kbuf, vT);
  k_attn<<<dim3(512), dim3(256), 0, stream>>>(qb, kbuf, vT, opart, mpart, lpart);
  k_proj_ln_tq<<<dim3(1024), dim3(256), 0, stream>>>(x, opart, mpart, lpart, projw, projb,
                                                     lns, lnb, wq, bq, h2, tqb16);
  k_crossf<<<dim3(256), dim3(256), 0, stream>>>(tqb16, tkb16, tvb16, wo, bo, h2, out);
}

// Round 14
// 75.934 us; speedup vs baseline: 1.2132x; 1.2132x over previous
//
#include <hip/hip_runtime.h>
#include <cstdint>
#include <cstddef>

#define BN 4
#define CN 64
#define NN 4096
#define GN 32
#define TN 77
#define DN 768
#define EPSV 1e-5f
#define SCALEV 0.125f
#define LOG2E 1.4426950408889634f
#define NSPLIT 8

typedef __bf16 bf16_t;
typedef __attribute__((ext_vector_type(8))) __bf16 bf16x8;
typedef __attribute__((ext_vector_type(4))) __bf16 bf16x4;
typedef __attribute__((ext_vector_type(4))) float f32x4;

#define EXP2(x) __builtin_amdgcn_exp2f(x)

__device__ __forceinline__ f32x4 mfma16(bf16x8 a, bf16x8 b, f32x4 c) {
  return __builtin_amdgcn_mfma_f32_16x16x32_bf16(a, b, c, 0, 0, 0);
}
__device__ __forceinline__ f32x4 zero4() { return (f32x4){0.f, 0.f, 0.f, 0.f}; }

// async global->LDS, 16B per lane; LDS dest is wave-uniform base + lane*16
__device__ __forceinline__ void gload16(const void* g, void* l) {
  __builtin_amdgcn_global_load_lds(
      (const __attribute__((address_space(1))) void*)g,
      (__attribute__((address_space(3))) void*)l, 16, 0, 0);
}

// fragment-order channel permutation for 64-ch rows (two K=32 frags)
__device__ __forceinline__ int fragpos(int o) {
  return ((o >> 2) & 3) * 16 + ((o >> 4) & 1) * 4 + ((o >> 5) & 1) * 8 + (o & 3);
}
// within-64 K-slot permutation (two K=32 chunks)
__device__ __forceinline__ int vperm(int p) {
  return (p & 32) + ((p >> 2) & 3) * 8 + ((p >> 4) & 1) * 4 + (p & 3);
}
// within-96 K-slot permutation (three K=32 chunks)
__device__ __forceinline__ int perm96(int t) {
  int u = t & 31;
  return (t & ~31) + (((u & 15) >> 2) << 3) + ((u >> 4) << 2) + (u & 3);
}

// ---------------- K1: GN partial stats (blocks 0-255) + tk/tv (blocks 256-639) ---------
__global__ __launch_bounds__(256) void k_pre(const float* __restrict__ x,
    float* __restrict__ gpart,
    const float* __restrict__ ctx,
    const float* __restrict__ wk, const float* __restrict__ bk,
    const float* __restrict__ wv, const float* __restrict__ bv,
    bf16_t* __restrict__ tko, bf16_t* __restrict__ tvo) {
  __shared__ float ss[4], ssq[4];
  __shared__ float cr[768];
  __shared__ float red[4][64];
  int bx = blockIdx.x;
  int tid = threadIdx.x;
  if (bx < 256) {
    const float4* base = reinterpret_cast<const float4*>(x + (size_t)bx * 4096);
    float s = 0.f, sq = 0.f;
    for (int i = tid; i < 1024; i += 256) {
      float4 v = base[i];
      s  += v.x + v.y + v.z + v.w;
      sq += v.x*v.x + v.y*v.y + v.z*v.z + v.w*v.w;
    }
    for (int off = 32; off; off >>= 1) { s += __shfl_down(s, off); sq += __shfl_down(sq, off); }
    int w = tid >> 6, l = tid & 63;
    if (l == 0) { ss[w] = s; ssq[w] = sq; }
    __syncthreads();
    if (tid == 0) {
      gpart[bx * 2]     = ss[0] + ss[1] + ss[2] + ss[3];
      gpart[bx * 2 + 1] = ssq[0] + ssq[1] + ssq[2] + ssq[3];
    }
    return;
  }
  int bt = bx - 256;
  int b = bt / 96, t = bt % 96;
  if (t >= 77) {
    if (tid < 64) {
      if (t < 80) tko[((size_t)(b * 80) + t) * 64 + tid] = (bf16_t)0.f;
      tvo[((size_t)(b * 64) + tid) * 96 + perm96(t)] = (bf16_t)0.f;
    }
    return;
  }
  const float* src = ctx + ((size_t)(b * TN) + t) * 768;
  for (int i = tid; i < 768; i += 256) cr[i] = src[i];
  __syncthreads();
  int o = tid & 63, sec = tid >> 6;
  int sel = sec & 1, dh = sec >> 1;
  const float* w = (sel ? wv : wk) + dh * 384 * 64;
  const float* c0 = cr + dh * 384;
  float acc = 0.f;
  for (int d = 0; d < 384; d++) acc += c0[d] * w[d * 64 + o];
  red[sec][o] = acc;
  __syncthreads();
  if (tid < 128) {
    int s2 = tid >> 6; int oo = tid & 63;
    float r = red[s2][oo] + red[s2 + 2][oo] + (s2 ? bv[oo] : bk[oo]);
    if (s2 == 0)
      tko[((size_t)(b * 80) + t) * 64 + (fragpos(oo) ^ ((t & 7) << 3))] = (bf16_t)r;
    else
      tvo[((size_t)(b * 64) + oo) * 96 + perm96(t)] = (bf16_t)r;
  }
}

// ---------------- K2: GN apply + QKV 1x1; 32-position tiles (512 blocks) ----------------
__global__ __launch_bounds__(256) void k_gn_qkv(const float* __restrict__ x,
    const float* __restrict__ gpart,
    const float* __restrict__ gns, const float* __restrict__ gnb,
    const float* __restrict__ qkvw, const float* __restrict__ qkvb,
    bf16_t* __restrict__ qb, bf16_t* __restrict__ kb, bf16_t* __restrict__ vT) {
  __shared__ float hn[64][36];
  __shared__ float wqkT[64][129];
  __shared__ float wv2[64][64];
  int bx = blockIdx.x; int b = bx >> 7; int t0 = (bx & 127) << 5;
  int tid = threadIdx.x;
  for (int i = tid; i < 2048; i += 256) {
    float4 v = reinterpret_cast<const float4*>(qkvw)[i];
    int base = i << 2; int o = base >> 6, cc = base & 63;
    wqkT[cc][o] = v.x; wqkT[cc + 1][o] = v.y; wqkT[cc + 2][o] = v.z; wqkT[cc + 3][o] = v.w;
  }
  for (int i = tid; i < 1024; i += 256) {
    float4 v = reinterpret_cast<const float4*>(qkvw + 8192)[i];
    int base = i << 2; int ch = base >> 6, cc = base & 63;
    *reinterpret_cast<float4*>(&wv2[ch][cc]) = v;
  }
  {
    int c = tid >> 2, p0 = (tid & 3) << 3;
    float4 gp = *reinterpret_cast<const float4*>(gpart + (((b << 5) + (c >> 1)) << 2));
    float mu = (gp.x + gp.z) * (1.f / 8192.f);
    float e2 = (gp.y + gp.w) * (1.f / 8192.f);
    float rs = rsqrtf(e2 - mu * mu + EPSV);
    float sc = gns[c] * rs, bi = gnb[c] - mu * sc;
    const float* xp = x + ((size_t)(b * 64 + c)) * NN + t0 + p0;
    float4 v1 = *reinterpret_cast<const float4*>(xp);
    float4 v2 = *reinterpret_cast<const float4*>(xp + 4);
    hn[c][p0+0] = v1.x*sc+bi; hn[c][p0+1] = v1.y*sc+bi;
    hn[c][p0+2] = v1.z*sc+bi; hn[c][p0+3] = v1.w*sc+bi;
    hn[c][p0+4] = v2.x*sc+bi; hn[c][p0+5] = v2.y*sc+bi;
    hn[c][p0+6] = v2.z*sc+bi; hn[c][p0+7] = v2.w*sc+bi;
  }
  __syncthreads();
  {
    int o0 = tid & 63, p0 = (tid >> 6) << 3;
    int pq = fragpos(o0);
    float acc0[8], acc1[8];
    float b0 = qkvb[o0], b1 = qkvb[64 + o0];
    #pragma unroll
    for (int m = 0; m < 8; m++) { acc0[m] = b0; acc1[m] = b1; }
    for (int cc = 0; cc < 64; ++cc) {
      float4 h0 = *reinterpret_cast<const float4*>(&hn[cc][p0]);
      float4 h1 = *reinterpret_cast<const float4*>(&hn[cc][p0 + 4]);
      float w0 = wqkT[cc][o0];
      float w1 = wqkT[cc][64 + o0];
      acc0[0] += h0.x*w0; acc0[1] += h0.y*w0; acc0[2] += h0.z*w0; acc0[3] += h0.w*w0;
      acc0[4] += h1.x*w0; acc0[5] += h1.y*w0; acc0[6] += h1.z*w0; acc0[7] += h1.w*w0;
      acc1[0] += h0.x*w1; acc1[1] += h0.y*w1; acc1[2] += h0.z*w1; acc1[3] += h0.w*w1;
      acc1[4] += h1.x*w1; acc1[5] += h1.y*w1; acc1[6] += h1.z*w1; acc1[7] += h1.w*w1;
    }
    size_t rowbase = ((size_t)(b * NN) + t0 + p0) << 6;
    #pragma unroll
    for (int j = 0; j < 8; j++) {
      qb[rowbase + ((size_t)j << 6) + pq] = (bf16_t)(acc0[j] * (SCALEV * LOG2E));
      kb[rowbase + ((size_t)j << 6) + (pq ^ (j << 3))] = (bf16_t)acc1[j];
    }
  }
  {
    int p2 = tid & 31, ob = tid >> 5;
    int kk = t0 + p2;
    int colsw = vperm(kk & 63) ^ (ob << 3);
    float acc[8];
    #pragma unroll
    for (int m = 0; m < 8; m++) acc[m] = qkvb[128 + ob + 8*m];
    for (int c0 = 0; c0 < 64; c0 += 4) {
      float h0 = hn[c0][p2], h1 = hn[c0+1][p2], h2 = hn[c0+2][p2], h3 = hn[c0+3][p2];
      #pragma unroll
      for (int m = 0; m < 8; m++) {
        float4 w4 = *reinterpret_cast<const float4*>(&wv2[ob + 8*m][c0]);
        acc[m] += h0*w4.x + h1*w4.y + h2*w4.z + h3*w4.w;
      }
    }
    size_t vbase = ((size_t)(b * 64)) * NN + (size_t)(kk & ~63) + colsw;
    #pragma unroll
    for (int m = 0; m < 8; m++)
      vT[vbase + (size_t)(ob + 8*m) * NN] = (bf16_t)acc[m];
  }
}

// ---------------- K3: flash self-attn, LDS double-buffer, KV-split x8 (round-10 exact) --
__global__ __launch_bounds__(256, 4) void k_attn(const bf16_t* __restrict__ qb,
    const bf16_t* __restrict__ kb, const bf16_t* __restrict__ vT,
    bf16_t* __restrict__ opart, float* __restrict__ mpart, float* __restrict__ lpart) {
  __shared__ __align__(16) bf16_t smem[2][8192];
  int bx = blockIdx.x;
  int xcd = bx & 7;
  int b = xcd >> 1;
  int inner = ((bx >> 3) << 1) | (xcd & 1);    // 0..255
  int split = inner >> 5;                      // 0..7
  int qblk = inner & 31;
  int tid = threadIdx.x; int w = tid >> 6, l = tid & 63;
  int lo = l & 15, g = l >> 4;
  int qbase = (qblk << 7) + (w << 5);
  const bf16_t* qrowA = qb + (((size_t)(b * NN) + qbase + lo) << 6) + g * 16;
  const bf16_t* qrowB = qrowA + (16 << 6);
  bf16x8 qfA0 = *reinterpret_cast<const bf16x8*>(qrowA);
  bf16x8 qfA1 = *reinterpret_cast<const bf16x8*>(qrowA + 8);
  bf16x8 qfB0 = *reinterpret_cast<const bf16x8*>(qrowB);
  bf16x8 qfB1 = *reinterpret_cast<const bf16x8*>(qrowB + 8);
  f32x4 oaccA[4], oaccB[4];
  #pragma unroll
  for (int nt = 0; nt < 4; nt++) {
    oaccA[nt] = zero4();
    oaccB[nt] = zero4();
  }
  float mA = -8.f, lA = 0.f, mB = -8.f, lB = 0.f;
  const bf16_t* kbB = kb + ((size_t)b * NN << 6);
  const bf16_t* vB  = vT + ((size_t)b * 64) * NN;
  int kt0 = split << 9;                        // 512 keys per split

  int off0 = tid * 8;
  int off1 = 2048 + tid * 8;
  int ch0 = off0 >> 6, sl0 = off0 & 63;
  int ch1 = off1 >> 6, sl1 = off1 & 63;

  {
    const bf16_t* kT = kbB + ((size_t)kt0 << 6);
    gload16(kT + off0, &smem[0][off0]);
    gload16(kT + off1, &smem[0][off1]);
    gload16(vB + (size_t)ch0 * NN + kt0 + sl0, &smem[0][4096 + off0]);
    gload16(vB + (size_t)ch1 * NN + kt0 + sl1, &smem[0][4096 + off1]);
  }
  __syncthreads();

  #pragma unroll 1
  for (int t = 0; t < 8; ++t) {
    int cur = t & 1;
    if (t < 7) {
      int kn = kt0 + ((t + 1) << 6);
      const bf16_t* kT = kbB + ((size_t)kn << 6);
      gload16(kT + off0, &smem[cur ^ 1][off0]);
      gload16(kT + off1, &smem[cur ^ 1][off1]);
      gload16(vB + (size_t)ch0 * NN + kn + sl0, &smem[cur ^ 1][4096 + off0]);
      gload16(vB + (size_t)ch1 * NN + kn + sl1, &smem[cur ^ 1][4096 + off1]);
    }
    const bf16_t* sK = smem[cur];
    const bf16_t* sV = smem[cur] + 4096;
    f32x4 sA[4], sB[4];
    #pragma unroll
    for (int c = 0; c < 4; c++) {
      int kk = (c << 4) + lo;
      int o1 = (g << 4) ^ ((kk & 7) << 3);
      bf16x8 kf0 = *reinterpret_cast<const bf16x8*>(sK + (kk << 6) + o1);
      bf16x8 kf1 = *reinterpret_cast<const bf16x8*>(sK + (kk << 6) + (o1 ^ 8));
      sA[c] = mfma16(kf0, qfA0, zero4());
      sA[c] = mfma16(kf1, qfA1, sA[c]);
      sB[c] = mfma16(kf0, qfB0, zero4());
      sB[c] = mfma16(kf1, qfB1, sB[c]);
    }
    float pmaxA = -1e30f, pmaxB = -1e30f;
    #pragma unroll
    for (int c = 0; c < 4; c++)
      #pragma unroll
      for (int r = 0; r < 4; r++) {
        pmaxA = fmaxf(pmaxA, sA[c][r]);
        pmaxB = fmaxf(pmaxB, sB[c][r]);
      }
    if (!__all(pmaxA - mA <= 8.f)) {
      pmaxA = fmaxf(pmaxA, __shfl_xor(pmaxA, 16));
      pmaxA = fmaxf(pmaxA, __shfl_xor(pmaxA, 32));
      float mn = fmaxf(mA, pmaxA);
      float corr = EXP2(mA - mn);
      lA *= corr; mA = mn;
      float fr[4];
      #pragma unroll
      for (int r = 0; r < 4; r++) fr[r] = __shfl(corr, (g << 2) + r);
      #pragma unroll
      for (int nt = 0; nt < 4; nt++)
        #pragma unroll
        for (int r = 0; r < 4; r++) oaccA[nt][r] *= fr[r];
    }
    if (!__all(pmaxB - mB <= 8.f)) {
      pmaxB = fmaxf(pmaxB, __shfl_xor(pmaxB, 16));
      pmaxB = fmaxf(pmaxB, __shfl_xor(pmaxB, 32));
      float mn = fmaxf(mB, pmaxB);
      float corr = EXP2(mB - mn);
      lB *= corr; mB = mn;
      float fr[4];
      #pragma unroll
      for (int r = 0; r < 4; r++) fr[r] = __shfl(corr, (g << 2) + r);
      #pragma unroll
      for (int nt = 0; nt < 4; nt++)
        #pragma unroll
        for (int r = 0; r < 4; r++) oaccB[nt][r] *= fr[r];
    }
    bf16x8 vf[4];
    #pragma unroll
    for (int nt = 0; nt < 4; nt++) {
      int ch = lo + (nt << 4);
      vf[nt] = *reinterpret_cast<const bf16x8*>(sV + (ch << 6) + ((g ^ (ch & 7)) << 3));
    }
    float lsA0 = 0.f, lsA1 = 0.f, lsB0 = 0.f, lsB1 = 0.f;
    #pragma unroll
    for (int c = 0; c < 4; c++)
      #pragma unroll
      for (int r = 0; r < 4; r++) {
        float pa = EXP2(sA[c][r] - mA);
        float pb = EXP2(sB[c][r] - mB);
        sA[c][r] = pa; sB[c][r] = pb;
        if (c & 1) { lsA1 += pa; lsB1 += pb; } else { lsA0 += pa; lsB0 += pb; }
      }
    lA += lsA0 + lsA1;
    lB += lsB0 + lsB1;
    bf16x8 paA0, paA1, paB0, paB1;
    #pragma unroll
    for (int i = 0; i < 8; i++) {
      paA0[i] = (bf16_t)sA[i >> 2][i & 3]; paA1[i] = (bf16_t)sA[2 + (i >> 2)][i & 3];
      paB0[i] = (bf16_t)sB[i >> 2][i & 3]; paB1[i] = (bf16_t)sB[2 + (i >> 2)][i & 3];
    }
    #pragma unroll
    for (int nt = 0; nt < 4; ++nt) {
      oaccA[nt] = mfma16(paA0, vf[nt], oaccA[nt]);
      oaccB[nt] = mfma16(paB0, vf[nt], oaccB[nt]);
    }
    #pragma unroll
    for (int nt = 0; nt < 4; nt++) {
      int ch = lo + (nt << 4);
      vf[nt] = *reinterpret_cast<const bf16x8*>(sV + (ch << 6) + (((4 + g) ^ (ch & 7)) << 3));
    }
    #pragma unroll
    for (int nt = 0; nt < 4; ++nt) {
      oaccA[nt] = mfma16(paA1, vf[nt], oaccA[nt]);
      oaccB[nt] = mfma16(paB1, vf[nt], oaccB[nt]);
    }
    __syncthreads();
  }

  lA += __shfl_xor(lA, 16); lA += __shfl_xor(lA, 32);
  lB += __shfl_xor(lB, 16); lB += __shfl_xor(lB, 32);

  size_t ob = ((size_t)(split * BN + b)) * NN + qbase;
  float liA[4], liB[4];
  #pragma unroll
  for (int r = 0; r < 4; r++) {
    liA[r] = 1.0f / __shfl(lA, (g << 2) + r);
    liB[r] = 1.0f / __shfl(lB, (g << 2) + r);
  }
  #pragma unroll
  for (int nt = 0; nt < 4; nt++)
    #pragma unroll
    for (int r = 0; r < 4; r++) {
      opart[((ob + (g << 2) + r) << 6) + lo + (nt << 4)] = (bf16_t)(oaccA[nt][r] * liA[r]);
      opart[((ob + 16 + (g << 2) + r) << 6) + lo + (nt << 4)] = (bf16_t)(oaccB[nt][r] * liB[r]);
    }
  if (l < 16) { mpart[ob + l] = mA; lpart[ob + l] = lA; }
  else if (l < 32) { mpart[ob + 16 + lo] = mB; lpart[ob + 16 + lo] = lB; }
}

// ---------------- K4: combine 8 splits + proj + residual ; LayerNorm ; tq(bf16) --------
// h2 stored bf16 (residual only; LN uses fp32 LDS copy)
__global__ __launch_bounds__(256) void k_proj_ln_tq(const float* __restrict__ x,
    const bf16_t* __restrict__ opart, const float* __restrict__ mpart, const float* __restrict__ lpart,
    const float* __restrict__ projw, const float* __restrict__ projb,
    const float* __restrict__ lns, const float* __restrict__ lnb,
    const float* __restrict__ wq, const float* __restrict__ bq,
    bf16_t* __restrict__ h2, bf16_t* __restrict__ tq) {
  __shared__ float wcomb[16][NSPLIT];
  __shared__ float sob[16][65];
  __shared__ float h2l[64][17];
  __shared__ float r1[16][16], r2[16][16];
  __shared__ float mu_s[16], rs_s[16];
  int bx = blockIdx.x; int b = bx >> 8; int t0 = (bx & 255) << 4;
  int tid = threadIdx.x;
  if (tid < 16) {
    int p = tid, q = t0 + p;
    float ms[NSPLIT];
    float mstar = -1e30f;
    #pragma unroll
    for (int s = 0; s < NSPLIT; s++) {
      ms[s] = mpart[((size_t)(s * BN + b)) * NN + q];
      mstar = fmaxf(mstar, ms[s]);
    }
    float co[NSPLIT]; float denom = 0.f;
    #pragma unroll
    for (int s = 0; s < NSPLIT; s++) {
      co[s] = EXP2(ms[s] - mstar) * lpart[((size_t)(s * BN + b)) * NN + q];
      denom += co[s];
    }
    float inv = 1.0f / denom;
    #pragma unroll
    for (int s = 0; s < NSPLIT; s++) wcomb[p][s] = co[s] * inv;
  }
  __syncthreads();
  {
    int p = tid >> 4, c0 = (tid & 15) << 2;
    int q = t0 + p;
    float acc[4] = {0.f, 0.f, 0.f, 0.f};
    #pragma unroll
    for (int s = 0; s < NSPLIT; s++) {
      bf16x4 v = *reinterpret_cast<const bf16x4*>(
          opart + ((((size_t)(s * BN + b)) * NN + q) << 6) + c0);
      float wv = wcomb[p][s];
      #pragma unroll
      for (int j = 0; j < 4; j++) acc[j] += wv * (float)v[j];
    }
    #pragma unroll
    for (int j = 0; j < 4; j++) sob[p][c0 + j] = acc[j];
  }
  __syncthreads();
  {
    int p = tid & 15, ob = tid >> 4;
    float acc[4];
    #pragma unroll
    for (int m = 0; m < 4; m++) {
      int o = ob + 16*m;
      acc[m] = projb[o] + x[((size_t)(b * 64) + o) * NN + t0 + p];
    }
    for (int cc = 0; cc < 64; ++cc) {
      float sv = sob[p][cc];
      #pragma unroll
      for (int m = 0; m < 4; m++) acc[m] += sv * projw[(ob + 16*m) * 64 + cc];
    }
    #pragma unroll
    for (int m = 0; m < 4; m++) {
      int o = ob + 16*m;
      h2[((size_t)(b * 64) + o) * NN + t0 + p] = (bf16_t)acc[m];
      h2l[o][p] = acc[m];
    }
  }
  __syncthreads();
  {
    int p = tid & 15, og = tid >> 4;
    float s = 0.f, sq = 0.f;
    #pragma unroll
    for (int j = 0; j < 4; j++) { float v = h2l[og * 4 + j][p]; s += v; sq += v*v; }
    r1[og][p] = s; r2[og][p] = sq;
  }
  __syncthreads();
  if (tid < 16) {
    float s = 0.f, sq = 0.f;
    #pragma unroll
    for (int j = 0; j < 16; j++) { s += r1[j][tid]; sq += r2[j][tid]; }
    float mu = s * (1.f/64.f);
    float var = sq * (1.f/64.f) - mu*mu;
    mu_s[tid] = mu; rs_s[tid] = rsqrtf(var + EPSV);
  }
  __syncthreads();
  {
    int p = tid & 15, cb = tid >> 4;
    float mu = mu_s[p], rs = rs_s[p];
    #pragma unroll
    for (int m = 0; m < 4; m++) {
      int c = cb + 16*m;
      sob[p][c] = (h2l[c][p] - mu) * rs * lns[c] + lnb[c];
    }
  }
  __syncthreads();
  {
    int o = tid & 63, pb = tid >> 6;
    int pq = fragpos(o);
    float acc[4];
    #pragma unroll
    for (int m = 0; m < 4; m++) acc[m] = bq[o];
    for (int cc = 0; cc < 64; ++cc) {
      float wv = wq[cc * 64 + o];
      #pragma unroll
      for (int m = 0; m < 4; m++) acc[m] += sob[pb + 4*m][cc] * wv;
    }
    #pragma unroll
    for (int m = 0; m < 4; m++) {
      int p = pb + 4*m;
      tq[(((size_t)(b * NN) + t0 + p) << 6) + pq] = (bf16_t)(acc[m] * (SCALEV * LOG2E));
    }
  }
}

// ---------------- K6: fused cross-attn (MFMA) + scramble GEMM + residual ----------------
// 256 blocks = (b, c1). 4 waves x 16 q-rows. h2 residual read as bf16.
__global__ __launch_bounds__(256) void k_crossf(const bf16_t* __restrict__ tq,
    const bf16_t* __restrict__ tk, const bf16_t* __restrict__ tv,
    const float* __restrict__ wo, const float* __restrict__ bo,
    const bf16_t* __restrict__ h2, float* __restrict__ out) {
  __shared__ __align__(16) bf16_t tkl[80][64];    // swizzled rows (pre-swizzled source)
  __shared__ __align__(16) bf16_t tvl[64][104];   // [ch][tok96] padded pitch
  __shared__ __align__(16) bf16_t woT[64][64];    // [w][kperm] swizzled
  __shared__ __align__(16) bf16_t toutT[64][64];  // [c2][kperm] swizzled
  int bx = blockIdx.x; int b = bx >> 6; int c1 = bx & 63;
  int tid = threadIdx.x; int wv_ = tid >> 6; int l = tid & 63;
  int lo = l & 15, g = l >> 4;
  {
    const uint4* src = reinterpret_cast<const uint4*>(tk + (size_t)b * 80 * 64);
    uint4* dst = reinterpret_cast<uint4*>(&tkl[0][0]);
    for (int i = tid; i < 640; i += 256) dst[i] = src[i];
  }
  {
    const uint4* src = reinterpret_cast<const uint4*>(tv + (size_t)b * 64 * 96);
    uint4* dst = reinterpret_cast<uint4*>(&tvl[0][0]);
    for (int i = tid; i < 768; i += 256) {
      int row = i / 12, j = i % 12;
      dst[row * 13 + j] = src[i];
    }
  }
  for (int i = tid; i < 4096; i += 256) {
    int k = i >> 6, w = i & 63;
    int vp = vperm(k);
    woT[w][(((vp >> 3) ^ (w & 7)) << 3) + (vp & 7)] = (bf16_t)wo[i];
  }
  __syncthreads();
  // Q fragments (global, fragpos rows)
  int n0 = (c1 << 6) + (wv_ << 4);
  const bf16_t* qrow = tq + (((size_t)(b * NN) + n0 + lo) << 6) + g * 16;
  bf16x8 qf0 = *reinterpret_cast<const bf16x8*>(qrow);
  bf16x8 qf1 = *reinterpret_cast<const bf16x8*>(qrow + 8);
  // QK^T: 5 token-tiles
  f32x4 sa[5];
  #pragma unroll
  for (int ti = 0; ti < 5; ti++) {
    int tok = ti * 16 + lo;
    int o1 = (g << 4) ^ ((tok & 7) << 3);
    bf16x8 kf0 = *reinterpret_cast<const bf16x8*>(&tkl[tok][0] + o1);
    bf16x8 kf1 = *reinterpret_cast<const bf16x8*>(&tkl[tok][0] + (o1 ^ 8));
    f32x4 z = mfma16(kf0, qf0, zero4());
    sa[ti] = mfma16(kf1, qf1, z);
  }
  // one-shot masked softmax (lane lo = q; tokens at ti*16 + g*4 + r)
  float p[5][4];
  float mx = -1e30f;
  #pragma unroll
  for (int ti = 0; ti < 5; ti++)
    #pragma unroll
    for (int r = 0; r < 4; r++)
      if (ti * 16 + (g << 2) + r < TN) mx = fmaxf(mx, sa[ti][r]);
  mx = fmaxf(mx, __shfl_xor(mx, 16));
  mx = fmaxf(mx, __shfl_xor(mx, 32));
  float ls = 0.f;
  #pragma unroll
  for (int ti = 0; ti < 5; ti++)
    #pragma unroll
    for (int r = 0; r < 4; r++) {
      float pv = (ti * 16 + (g << 2) + r < TN) ? EXP2(sa[ti][r] - mx) : 0.f;
      p[ti][r] = pv; ls += pv;
    }
  ls += __shfl_xor(ls, 16); ls += __shfl_xor(ls, 32);
  float linv = 1.0f / ls;
  // P -> A fragments (3 chunks of K=32), zero-shuffle
  bf16x8 pa[3];
  #pragma unroll
  for (int c = 0; c < 3; c++)
    #pragma unroll
    for (int i = 0; i < 8; i++)
      pa[c][i] = (bf16_t)p[2 * c + (i >> 2)][i & 3];
  // PV: 3 chunks x 4 ch-tiles
  f32x4 oacc[4];
  #pragma unroll
  for (int nt = 0; nt < 4; nt++) oacc[nt] = zero4();
  #pragma unroll
  for (int c = 0; c < 3; c++)
    #pragma unroll
    for (int nt = 0; nt < 4; nt++) {
      bf16x8 vf = *reinterpret_cast<const bf16x8*>(&tvl[nt * 16 + lo][0] + c * 32 + g * 8);
      oacc[nt] = mfma16(pa[c], vf, oacc[nt]);
    }
  // normalize + write O^T to LDS (toutT[ch][vperm(qlocal)] with group swizzle)
  float li[4];
  #pragma unroll
  for (int r = 0; r < 4; r++) li[r] = __shfl(linv, (g << 2) + r);
  int hh = wv_ & 1, cp = wv_ >> 1;
  #pragma unroll
  for (int nt = 0; nt < 4; nt++) {
    int ch = nt * 16 + lo;
    int basegroup = cp * 4 + g;
    int col = ((basegroup ^ (ch & 7)) << 3) + hh * 4;
    bf16_t tmp[4];
    #pragma unroll
    for (int r = 0; r < 4; r++) tmp[r] = (bf16_t)(oacc[nt][r] * li[r]);
    *reinterpret_cast<uint2*>(&toutT[ch][col]) = *reinterpret_cast<const uint2*>(tmp);
  }
  __syncthreads();
  // final GEMM: D[c2 = wv*16 + ..., w] = toutT x woT ; wave owns 16 c2-rows
  f32x4 o2[4];
  #pragma unroll
  for (int wt = 0; wt < 4; wt++) o2[wt] = zero4();
  #pragma unroll
  for (int f = 0; f < 2; f++) {
    int c2r = wv_ * 16 + lo;
    int agrp = ((f * 4 + g) ^ (c2r & 7)) << 3;
    bf16x8 af = *reinterpret_cast<const bf16x8*>(&toutT[c2r][agrp]);
    #pragma unroll
    for (int wt = 0; wt < 4; wt++) {
      int wrow = wt * 16 + lo;
      int bgrp = ((f * 4 + g) ^ (wrow & 7)) << 3;
      bf16x8 bf_ = *reinterpret_cast<const bf16x8*>(&woT[wrow][bgrp]);
      o2[wt] = mfma16(af, bf_, o2[wt]);
    }
  }
  // epilogue: out = GEMM + h2 + bo
  const bf16_t* h2r = h2 + ((size_t)(b * 64) + c1) * NN;
  float* outr = out + ((size_t)(b * 64) + c1) * NN;
  float bov[4];
  #pragma unroll
  for (int wt = 0; wt < 4; wt++) bov[wt] = bo[wt * 16 + lo];
  #pragma unroll
  for (int wt = 0; wt < 4; wt++)
    #pragma unroll
    for (int r = 0; r < 4; r++) {
      int c2 = wv_ * 16 + (g << 2) + r;
      int pos = (c2 << 6) + wt * 16 + lo;
      outr[pos] = o2[wt][r] + (float)h2r[pos] + bov[wt];
    }
}

extern "C" void kernel_launch(void* const* d_in, const int* in_sizes, int n_in,
                              void* d_out, int out_size, void* d_ws, size_t ws_size,
                              hipStream_t stream) {
  const float* x     = (const float*)d_in[0];
  const float* ctx   = (const float*)d_in[1];
  const float* gns   = (const float*)d_in[2];
  const float* gnb   = (const float*)d_in[3];
  const float* qkvw  = (const float*)d_in[4];
  const float* qkvb  = (const float*)d_in[5];
  const float* projw = (const float*)d_in[6];
  const float* projb = (const float*)d_in[7];
  const float* lns   = (const float*)d_in[8];
  const float* lnb   = (const float*)d_in[9];
  const float* wq    = (const float*)d_in[10];
  const float* bq    = (const float*)d_in[11];
  const float* wk    = (const float*)d_in[12];
  const float* bk    = (const float*)d_in[13];
  const float* wv    = (const float*)d_in[14];
  const float* bv    = (const float*)d_in[15];
  const float* wo    = (const float*)d_in[16];
  const float* bo    = (const float*)d_in[17];
  float* out = (float*)d_out;

  char* ws = (char*)d_ws;
  float* gpart = (float*)ws;                       // 2 KB
  bf16_t* qb   = (bf16_t*)(ws + 4096);             // 2 MB
  bf16_t* kbuf = qb + (size_t)BN * NN * 64;        // 2 MB (swizzled)
  bf16_t* vT   = kbuf + (size_t)BN * NN * 64;      // 2 MB (swizzled)
  bf16_t* opart = vT + (size_t)BN * NN * 64;       // 16 MB bf16 (8 splits)
  float* mpart = (float*)(opart + (size_t)NSPLIT * BN * NN * 64);   // 512 KB
  float* lpart = mpart + (size_t)NSPLIT * BN * NN;                  // 512 KB
  bf16_t* h2   = (bf16_t*)(lpart + (size_t)NSPLIT * BN * NN);      // 2 MB bf16
  bf16_t* tkb16 = h2 + (size_t)BN * NN * 64;                        // 40 KB
  bf16_t* tvb16 = tkb16 + (size_t)BN * 80 * 64;                     // 48 KB
  // aliased: tq (bf16, 2 MB) over dead qb after k_attn
  bf16_t* tqb16 = qb;

  k_pre<<<dim3(256 + BN * 96), dim3(256), 0, stream>>>(x, gpart, ctx, wk, bk, wv, bv,
                                                       tkb16, tvb16);
  k_gn_qkv<<<dim3(512), dim3(256), 0, stream>>>(x, gpart, gns, gnb, qkvw, qkvb,
                                                qb, kbuf, vT);
  k_attn<<<dim3(1024), dim3(256), 0, stream>>>(qb, kbuf, vT, opart, mpart, lpart);
  k_proj_ln_tq<<<dim3(1024), dim3(256), 0, stream>>>(x, opart, mpart, lpart, projw, projb,
                                                     lns, lnb, wq, bq, h2, tqb16);
  k_crossf<<<dim3(256), dim3(256), 0, stream>>>(tqb16, tkb16, tvb16, wo, bo, h2, out);
}